// Round 1
// baseline (3817.482 us; speedup 1.0000x reference)
//
#include <hip/hip_runtime.h>

#define N_NODES 50000
#define N_GENE  40000
#define N_GOID  10000
#define N_EDGES 800000
#define GOID_DIM 4096
#define GO_HID  1024
#define D_IN    512
#define HID1    512
#define HID2    256

// ---------------- CSR build ----------------
__global__ void k_zero(int* __restrict__ p, int n) {
    int i = blockIdx.x * 256 + threadIdx.x;
    if (i < n) p[i] = 0;
}

__global__ void k_count(const int* __restrict__ dst, int* __restrict__ counts) {
    int e = blockIdx.x * 256 + threadIdx.x;
    if (e < N_EDGES) atomicAdd(&counts[dst[e]], 1);
}

__global__ __launch_bounds__(1024)
void k_scan(const int* __restrict__ counts, int* __restrict__ rowptr,
            int* __restrict__ cursor, float* __restrict__ dinv) {
    __shared__ int part[1024];
    const int CHUNK = (N_NODES + 1023) / 1024;  // 49
    int t = threadIdx.x;
    int beg = t * CHUNK;
    int end = min(beg + CHUNK, N_NODES);
    int s = 0;
    for (int i = beg; i < end; ++i) s += counts[i];
    part[t] = s;
    __syncthreads();
    // Hillis-Steele inclusive scan over 1024 partials
    for (int off = 1; off < 1024; off <<= 1) {
        int v = (t >= off) ? part[t - off] : 0;
        __syncthreads();
        part[t] += v;
        __syncthreads();
    }
    int excl = (t == 0) ? 0 : part[t - 1];
    for (int i = beg; i < end; ++i) {
        int c = counts[i];
        rowptr[i] = excl;
        cursor[i] = excl;
        dinv[i] = rsqrtf(1.0f + (float)c);
        excl += c;
    }
    if (t == 1023) rowptr[N_NODES] = part[1023];
}

__global__ void k_fill(const int* __restrict__ src, const int* __restrict__ dst,
                       int* __restrict__ cursor, int* __restrict__ csr_src) {
    int e = blockIdx.x * 256 + threadIdx.x;
    if (e < N_EDGES) {
        int d = dst[e];
        int pos = atomicAdd(&cursor[d], 1);
        csr_src[pos] = src[e];
    }
}

// ---------------- xt assembly: gene rows are x[:,0:512] ----------------
__global__ void k_copy_gene(const float* __restrict__ x, float* __restrict__ xt) {
    int idx = blockIdx.x * 256 + threadIdx.x;  // over N_GENE*128 float4s
    int row = idx >> 7;
    int c = idx & 127;
    if (row < N_GENE)
        ((float4*)xt)[(size_t)row * 128 + c] =
            ((const float4*)x)[(size_t)row * 1024 + c];  // x row = 4096 f = 1024 f4
}

// ---------------- SGEMM: C(MxN) = A(MxK, lda) @ B(KxN) [+epilogue] ----------------
#define EPI_NONE 0
#define EPI_BIAS_RELU 1
#define EPI_SCALE 2

template <int EPI>
__global__ __launch_bounds__(256)
void k_gemm(const float* __restrict__ A, int lda,
            const float* __restrict__ B,
            const float* __restrict__ bias,
            const float* __restrict__ rowscale,
            float* __restrict__ C, int M, int N, int K) {
    __shared__ float As[16][128];  // [k][m]
    __shared__ float Bs[16][128];  // [k][n]
    int tid = threadIdx.x;
    int bm = blockIdx.y * 128, bn = blockIdx.x * 128;

    // A-tile loads: 128 rows x 16 k, 2 float4 per thread
    int ar = tid >> 2;           // 0..63
    int ak = (tid & 3) * 4;      // 0,4,8,12
    int r0 = min(bm + ar, M - 1);
    int r1 = min(bm + ar + 64, M - 1);
    const float* Ap0 = A + (size_t)r0 * lda + ak;
    const float* Ap1 = A + (size_t)r1 * lda + ak;

    // B-tile loads: 16 k x 128 n, 2 float4 per thread
    int bk = tid >> 5;           // 0..7
    int bnq = (tid & 31) * 4;
    const float* Bp0 = B + (size_t)bk * N + bn + bnq;
    const float* Bp1 = B + (size_t)(bk + 8) * N + bn + bnq;

    int ty = tid >> 4, tx = tid & 15;
    float acc[8][8];
#pragma unroll
    for (int i = 0; i < 8; i++)
#pragma unroll
        for (int j = 0; j < 8; j++) acc[i][j] = 0.0f;

    for (int k0 = 0; k0 < K; k0 += 16) {
        float4 a0 = *(const float4*)(Ap0 + k0);
        float4 a1 = *(const float4*)(Ap1 + k0);
        float4 b0 = *(const float4*)(Bp0 + (size_t)k0 * N);
        float4 b1 = *(const float4*)(Bp1 + (size_t)k0 * N);
        As[ak + 0][ar] = a0.x;
        As[ak + 1][ar] = a0.y;
        As[ak + 2][ar] = a0.z;
        As[ak + 3][ar] = a0.w;
        As[ak + 0][ar + 64] = a1.x;
        As[ak + 1][ar + 64] = a1.y;
        As[ak + 2][ar + 64] = a1.z;
        As[ak + 3][ar + 64] = a1.w;
        *(float4*)&Bs[bk][bnq] = b0;
        *(float4*)&Bs[bk + 8][bnq] = b1;
        __syncthreads();
#pragma unroll
        for (int k = 0; k < 16; ++k) {
            float a[8], b[8];
            *(float4*)&a[0] = *(const float4*)&As[k][ty * 8];
            *(float4*)&a[4] = *(const float4*)&As[k][ty * 8 + 4];
            *(float4*)&b[0] = *(const float4*)&Bs[k][tx * 8];
            *(float4*)&b[4] = *(const float4*)&Bs[k][tx * 8 + 4];
#pragma unroll
            for (int i = 0; i < 8; i++)
#pragma unroll
                for (int j = 0; j < 8; j++)
                    acc[i][j] = fmaf(a[i], b[j], acc[i][j]);
        }
        __syncthreads();
    }

#pragma unroll
    for (int i = 0; i < 8; i++) {
        int m = bm + ty * 8 + i;
        if (m < M) {
            float scale = (EPI == EPI_SCALE) ? rowscale[m] : 1.0f;
#pragma unroll
            for (int jj = 0; jj < 8; jj += 4) {
                int n = bn + tx * 8 + jj;
                float4 v;
                v.x = acc[i][jj + 0];
                v.y = acc[i][jj + 1];
                v.z = acc[i][jj + 2];
                v.w = acc[i][jj + 3];
                if (EPI == EPI_BIAS_RELU) {
                    const float4 bb = *(const float4*)&bias[n];
                    v.x = fmaxf(v.x + bb.x, 0.0f);
                    v.y = fmaxf(v.y + bb.y, 0.0f);
                    v.z = fmaxf(v.z + bb.z, 0.0f);
                    v.w = fmaxf(v.w + bb.w, 0.0f);
                } else if (EPI == EPI_SCALE) {
                    v.x *= scale;
                    v.y *= scale;
                    v.z *= scale;
                    v.w *= scale;
                }
                *(float4*)&C[(size_t)m * N + n] = v;
            }
        }
    }
}

// ---------------- aggregation + residual combine ----------------
// h[i] = relu(dinv[i] * (sum_{e:dst=i} hwS[src] + hwS[i]) + bc) + r[i] + br
// where hwS = dinv[row] * (A @ Wc)  (pre-scaled by GEMM epilogue)
template <int F>
__global__ void k_combine(const float* __restrict__ hwS, const float* __restrict__ r,
                          const float* __restrict__ dinv,
                          const int* __restrict__ rowptr, const int* __restrict__ csr_src,
                          const float* __restrict__ bc, const float* __restrict__ br,
                          float* __restrict__ h) {
    int node = blockIdx.x;
    int c = threadIdx.x * 4;
    int beg = rowptr[node], end = rowptr[node + 1];
    float4 acc = *(const float4*)&hwS[(size_t)node * F + c];  // self term
    for (int e = beg; e < end; ++e) {
        int s = csr_src[e];
        const float4 v = *(const float4*)&hwS[(size_t)s * F + c];
        acc.x += v.x;
        acc.y += v.y;
        acc.z += v.z;
        acc.w += v.w;
    }
    float di = dinv[node];
    const float4 vb = *(const float4*)&bc[c];
    const float4 vr = *(const float4*)&r[(size_t)node * F + c];
    const float4 vbr = *(const float4*)&br[c];
    float4 o;
    o.x = fmaxf(fmaf(di, acc.x, vb.x), 0.0f) + vr.x + vbr.x;
    o.y = fmaxf(fmaf(di, acc.y, vb.y), 0.0f) + vr.y + vbr.y;
    o.z = fmaxf(fmaf(di, acc.z, vb.z), 0.0f) + vr.z + vbr.z;
    o.w = fmaxf(fmaf(di, acc.w, vb.w), 0.0f) + vr.w + vbr.w;
    *(float4*)&h[(size_t)node * F + c] = o;
}

// ---------------- final projection: out = [h2[:40000], istj] @ W_f + b_f ----------------
__global__ __launch_bounds__(256)
void k_final(const float* __restrict__ h2, const float* __restrict__ istj,
             const float* __restrict__ Wf, const float* __restrict__ bf,
             float* __restrict__ out) {
    __shared__ float w0[257], w1[257];
    int t = threadIdx.x;
    for (int i = t; i < 257; i += 256) {
        w0[i] = Wf[2 * i];
        w1[i] = Wf[2 * i + 1];
    }
    __syncthreads();
    int wave = t >> 6, lane = t & 63;
    int row = blockIdx.x * 4 + wave;
    if (row >= N_GENE) return;
    const float4 v = *(const float4*)&h2[(size_t)row * HID2 + lane * 4];
    int c = lane * 4;
    float s0 = v.x * w0[c] + v.y * w0[c + 1] + v.z * w0[c + 2] + v.w * w0[c + 3];
    float s1 = v.x * w1[c] + v.y * w1[c + 1] + v.z * w1[c + 2] + v.w * w1[c + 3];
    for (int off = 32; off > 0; off >>= 1) {
        s0 += __shfl_down(s0, off);
        s1 += __shfl_down(s1, off);
    }
    if (lane == 0) {
        float it = istj[row];
        out[(size_t)row * 2 + 0] = s0 + it * w0[256] + bf[0];
        out[(size_t)row * 2 + 1] = s1 + it * w1[256] + bf[1];
    }
}

extern "C" void kernel_launch(void* const* d_in, const int* in_sizes, int n_in,
                              void* d_out, int out_size, void* d_ws, size_t ws_size,
                              hipStream_t stream) {
    const float* x     = (const float*)d_in[0];
    const int*   ei    = (const int*)d_in[1];
    const float* istj  = (const float*)d_in[2];
    // d_in[3] = n_gene (compile-time constant here)
    const float* W_go1 = (const float*)d_in[4];
    const float* b_go1 = (const float*)d_in[5];
    const float* W_go2 = (const float*)d_in[6];
    const float* b_go2 = (const float*)d_in[7];
    const float* W_c1  = (const float*)d_in[8];
    const float* b_c1  = (const float*)d_in[9];
    const float* W_c2  = (const float*)d_in[10];
    const float* b_c2  = (const float*)d_in[11];
    const float* W_r1  = (const float*)d_in[12];
    const float* b_r1  = (const float*)d_in[13];
    const float* W_r2  = (const float*)d_in[14];
    const float* b_r2  = (const float*)d_in[15];
    const float* W_f   = (const float*)d_in[16];
    const float* b_f   = (const float*)d_in[17];
    float* out = (float*)d_out;

    // workspace carve-up (~363 MB)
    char* w = (char*)d_ws;
    size_t off = 0;
    auto alloc = [&](size_t bytes) -> void* {
        void* p = w + off;
        off += (bytes + 255) & ~(size_t)255;
        return p;
    };
    float* xt   = (float*)alloc((size_t)N_NODES * D_IN * 4);   // xt, later h1
    float* bufB = (float*)alloc((size_t)N_NODES * HID1 * 4);   // hw1S, later hw2S
    float* bufC = (float*)alloc((size_t)N_NODES * HID1 * 4);   // r1, later r2
    float* regE = (float*)alloc((size_t)N_NODES * HID2 * 4);   // g1 (early), h2 (late)
    float* g1   = regE;  // 10000*1024 floats fits in 50000*256
    float* dinv = (float*)alloc((size_t)N_NODES * 4);
    int* counts = (int*)alloc((size_t)N_NODES * 4);
    int* rowptr = (int*)alloc((size_t)(N_NODES + 1) * 4);
    int* cursor = (int*)alloc((size_t)N_NODES * 4);
    int* csr    = (int*)alloc((size_t)N_EDGES * 4);

    const int* srcp = ei;
    const int* dstp = ei + N_EDGES;

    // CSR + degree norm
    k_zero<<<(N_NODES + 255) / 256, 256, 0, stream>>>(counts, N_NODES);
    k_count<<<(N_EDGES + 255) / 256, 256, 0, stream>>>(dstp, counts);
    k_scan<<<1, 1024, 0, stream>>>(counts, rowptr, cursor, dinv);
    k_fill<<<(N_EDGES + 255) / 256, 256, 0, stream>>>(srcp, dstp, cursor, csr);

    // xt rows 0..39999 from x[:,:512]
    k_copy_gene<<<(N_GENE * 128) / 256, 256, 0, stream>>>(x, xt);

    // GOID MLP: g1 = relu(x[40000:] @ W_go1 + b); xt[40000:] = relu(g1 @ W_go2 + b)
    k_gemm<EPI_BIAS_RELU><<<dim3(GO_HID / 128, (N_GOID + 127) / 128), 256, 0, stream>>>(
        x + (size_t)N_GENE * GOID_DIM, GOID_DIM, W_go1, b_go1, nullptr, g1,
        N_GOID, GO_HID, GOID_DIM);
    k_gemm<EPI_BIAS_RELU><<<dim3(D_IN / 128, (N_GOID + 127) / 128), 256, 0, stream>>>(
        g1, GO_HID, W_go2, b_go2, nullptr, xt + (size_t)N_GENE * D_IN,
        N_GOID, D_IN, GO_HID);

    // conv1: hw1S = dinv ⊙ (xt @ W_c1); r1 = xt @ W_r1
    k_gemm<EPI_SCALE><<<dim3(HID1 / 128, (N_NODES + 127) / 128), 256, 0, stream>>>(
        xt, D_IN, W_c1, nullptr, dinv, bufB, N_NODES, HID1, D_IN);
    k_gemm<EPI_NONE><<<dim3(HID1 / 128, (N_NODES + 127) / 128), 256, 0, stream>>>(
        xt, D_IN, W_r1, nullptr, nullptr, bufC, N_NODES, HID1, D_IN);
    // h1 (into xt)
    k_combine<HID1><<<N_NODES, HID1 / 4, 0, stream>>>(bufB, bufC, dinv, rowptr, csr,
                                                      b_c1, b_r1, xt);

    // conv2: hw2S = dinv ⊙ (h1 @ W_c2); r2 = h1 @ W_r2
    k_gemm<EPI_SCALE><<<dim3(HID2 / 128, (N_NODES + 127) / 128), 256, 0, stream>>>(
        xt, HID1, W_c2, nullptr, dinv, bufB, N_NODES, HID2, HID1);
    k_gemm<EPI_NONE><<<dim3(HID2 / 128, (N_NODES + 127) / 128), 256, 0, stream>>>(
        xt, HID1, W_r2, nullptr, nullptr, bufC, N_NODES, HID2, HID1);
    // h2 (into regE)
    k_combine<HID2><<<N_NODES, HID2 / 4, 0, stream>>>(bufB, bufC, dinv, rowptr, csr,
                                                      b_c2, b_r2, regE);

    // final 257->2 projection for gene rows
    k_final<<<(N_GENE + 3) / 4, 256, 0, stream>>>(regE, istj, W_f, b_f, out);
}

// Round 2
// 1756.858 us; speedup vs baseline: 2.1729x; 2.1729x over previous
//
#include <hip/hip_runtime.h>

#define N_NODES 50000
#define N_GENE  40000
#define N_GOID  10000
#define N_EDGES 800000
#define GOID_DIM 4096
#define GO_HID  1024
#define D_IN    512
#define HID1    512
#define HID2    256

typedef __bf16 bf16x8 __attribute__((ext_vector_type(8)));
typedef float v4f __attribute__((ext_vector_type(4)));

__device__ __forceinline__ unsigned short f2bf(float f) {
    unsigned int u = __float_as_uint(f);
    u += 0x7FFF + ((u >> 16) & 1);   // round-to-nearest-even
    return (unsigned short)(u >> 16);
}
__device__ __forceinline__ float b2f(unsigned short h) {
    return __uint_as_float(((unsigned int)h) << 16);
}
__device__ __forceinline__ unsigned int pack2(float a, float b) {
    return (unsigned int)f2bf(a) | ((unsigned int)f2bf(b) << 16);
}
__device__ __forceinline__ void gload_lds16(const unsigned short* g, unsigned short* l) {
    __builtin_amdgcn_global_load_lds(
        (const __attribute__((address_space(1))) unsigned int*)g,
        (__attribute__((address_space(3))) unsigned int*)l, 16, 0, 0);
}

// ---------------- CSR build ----------------
__global__ void k_zero(int* __restrict__ p, int n) {
    int i = blockIdx.x * 256 + threadIdx.x;
    if (i < n) p[i] = 0;
}

__global__ void k_count(const int* __restrict__ dst, int* __restrict__ counts) {
    int e = blockIdx.x * 256 + threadIdx.x;
    if (e < N_EDGES) atomicAdd(&counts[dst[e]], 1);
}

__global__ __launch_bounds__(1024)
void k_scan(const int* __restrict__ counts, int* __restrict__ rowptr,
            int* __restrict__ cursor, float* __restrict__ dinv) {
    __shared__ int part[1024];
    const int CHUNK = (N_NODES + 1023) / 1024;
    int t = threadIdx.x;
    int beg = t * CHUNK;
    int end = min(beg + CHUNK, N_NODES);
    int s = 0;
    for (int i = beg; i < end; ++i) s += counts[i];
    part[t] = s;
    __syncthreads();
    for (int off = 1; off < 1024; off <<= 1) {
        int v = (t >= off) ? part[t - off] : 0;
        __syncthreads();
        part[t] += v;
        __syncthreads();
    }
    int excl = (t == 0) ? 0 : part[t - 1];
    for (int i = beg; i < end; ++i) {
        int c = counts[i];
        rowptr[i] = excl;
        cursor[i] = excl;
        dinv[i] = rsqrtf(1.0f + (float)c);
        excl += c;
    }
    if (t == 1023) rowptr[N_NODES] = part[1023];
}

__global__ void k_fill(const int* __restrict__ src, const int* __restrict__ dst,
                       int* __restrict__ cursor, int* __restrict__ csr_src) {
    int e = blockIdx.x * 256 + threadIdx.x;
    if (e < N_EDGES) {
        int d = dst[e];
        int pos = atomicAdd(&cursor[d], 1);
        csr_src[pos] = src[e];
    }
}

// ---------------- conversions ----------------
// gene rows: x[:,0:512] fp32 -> xt bf16
__global__ void k_copy_gene_bf(const float* __restrict__ x, unsigned short* __restrict__ xt) {
    int idx = blockIdx.x * 256 + threadIdx.x;  // N_GENE*64 threads, 8 cols each
    int row = idx >> 6, c8 = (idx & 63) * 8;
    if (row >= N_GENE) return;
    const float4* s = (const float4*)(x + (size_t)row * GOID_DIM + c8);
    float4 a = s[0], b = s[1];
    uint4 u;
    u.x = pack2(a.x, a.y); u.y = pack2(a.z, a.w);
    u.z = pack2(b.x, b.y); u.w = pack2(b.z, b.w);
    *(uint4*)(xt + (size_t)row * D_IN + c8) = u;
}

// flat fp32 -> bf16 (8 elems / thread)
__global__ void k_f2bf8(const float* __restrict__ src, unsigned short* __restrict__ dst, int n8) {
    int i = blockIdx.x * 256 + threadIdx.x;
    if (i >= n8) return;
    const float4* s = (const float4*)src;
    float4 a = s[2 * (size_t)i], b = s[2 * (size_t)i + 1];
    uint4 u;
    u.x = pack2(a.x, a.y); u.y = pack2(a.z, a.w);
    u.z = pack2(b.x, b.y); u.w = pack2(b.z, b.w);
    ((uint4*)dst)[i] = u;
}

// W (KxN fp32) -> Wt (NxK bf16)
__global__ void k_wt(const float* __restrict__ W, unsigned short* __restrict__ Wt,
                     int K, int N) {
    __shared__ float t[32][33];
    int k0 = blockIdx.y * 32, n0 = blockIdx.x * 32;
    int tx = threadIdx.x, ty = threadIdx.y;  // (32,8)
#pragma unroll
    for (int i = 0; i < 4; ++i)
        t[ty + i * 8][tx] = W[(size_t)(k0 + ty + i * 8) * N + n0 + tx];
    __syncthreads();
#pragma unroll
    for (int i = 0; i < 4; ++i)
        Wt[(size_t)(n0 + ty + i * 8) * K + k0 + tx] = f2bf(t[tx][ty + i * 8]);
}

// ---------------- bf16 MFMA GEMM: C(MxN) = A(MxK) @ Bt(NxK)^T ----------------
#define EPI_BIAS_RELU 0
#define EPI_SCALE 1
#define EPI_PLAIN 2

template <int EPI>
__global__ __launch_bounds__(256)
void k_gemm_bf(const unsigned short* __restrict__ A,
               const unsigned short* __restrict__ Bt,
               const float* __restrict__ bias,
               const float* __restrict__ rowscale,
               unsigned short* __restrict__ C,
               int M, int N, int K) {
    __shared__ unsigned short As[128 * 32];  // [row][k] row-major
    __shared__ unsigned short Bs[128 * 32];  // [col][k] row-major
    int tid = threadIdx.x;
    int l = tid & 63, w = tid >> 6;
    int bm = blockIdx.y * 128, bn = blockIdx.x * 128;

    // staging: lane l of wave w covers rows w*16 + (l>>2) (+64 for round 1), k-chunk (l&3)*8
    int srow = w * 16 + (l >> 2);
    int sk = (l & 3) * 8;
    int am0 = min(bm + srow, M - 1);
    int am1 = min(bm + srow + 64, M - 1);
    const unsigned short* ag0 = A + (size_t)am0 * K + sk;
    const unsigned short* ag1 = A + (size_t)am1 * K + sk;
    const unsigned short* bg0 = Bt + (size_t)(bn + srow) * K + sk;
    const unsigned short* bg1 = Bt + (size_t)(bn + srow + 64) * K + sk;
    unsigned short* al0 = &As[w * 512];
    unsigned short* al1 = &As[2048 + w * 512];
    unsigned short* bl0 = &Bs[w * 512];
    unsigned short* bl1 = &Bs[2048 + w * 512];

    int wm = w & 1, wn = w >> 1;
    int row16 = l & 15, half = l >> 4;
    const unsigned short* Abase = &As[(wm * 64 + row16) * 32 + half * 8];
    const unsigned short* Bbase = &Bs[(wn * 64 + row16) * 32 + half * 8];

    v4f acc[4][4];
#pragma unroll
    for (int i = 0; i < 4; ++i)
#pragma unroll
        for (int j = 0; j < 4; ++j) acc[i][j] = (v4f){0.f, 0.f, 0.f, 0.f};

    for (int k0 = 0; k0 < K; k0 += 32) {
        gload_lds16(ag0, al0);
        gload_lds16(ag1, al1);
        gload_lds16(bg0, bl0);
        gload_lds16(bg1, bl1);
        ag0 += 32; ag1 += 32; bg0 += 32; bg1 += 32;
        __syncthreads();
        bf16x8 af[4], bf_[4];
#pragma unroll
        for (int t = 0; t < 4; ++t) {
            af[t] = *(const bf16x8*)(Abase + t * 16 * 32);
            bf_[t] = *(const bf16x8*)(Bbase + t * 16 * 32);
        }
#pragma unroll
        for (int i = 0; i < 4; ++i)
#pragma unroll
            for (int j = 0; j < 4; ++j)
                acc[i][j] = __builtin_amdgcn_mfma_f32_16x16x32_bf16(af[i], bf_[j], acc[i][j], 0, 0, 0);
        __syncthreads();
    }

#pragma unroll
    for (int mt = 0; mt < 4; ++mt) {
#pragma unroll
        for (int r = 0; r < 4; ++r) {
            int m = bm + wm * 64 + mt * 16 + half * 4 + r;
            if (m < M) {
                float sc = (EPI == EPI_SCALE) ? rowscale[m] : 0.f;
#pragma unroll
                for (int nt = 0; nt < 4; ++nt) {
                    int n = bn + wn * 64 + nt * 16 + row16;
                    float v = acc[mt][nt][r];
                    if (EPI == EPI_BIAS_RELU) v = fmaxf(v + bias[n], 0.f);
                    else if (EPI == EPI_SCALE) v = v * sc;
                    C[(size_t)m * N + n] = f2bf(v);
                }
            }
        }
    }
}

// ---------------- aggregation + residual combine (bf16 in) ----------------
// out[i] = relu(dinv[i]*(sum_{src->i} hwS[src] + hwS[i]) + bc) + r[i] + br
template <int F, bool OUT_BF16>
__global__ void k_combine(const unsigned short* __restrict__ hwS,
                          const unsigned short* __restrict__ rres,
                          const float* __restrict__ dinv,
                          const int* __restrict__ rowptr, const int* __restrict__ csr_src,
                          const float* __restrict__ bc, const float* __restrict__ br,
                          void* __restrict__ out) {
    int node = blockIdx.x;
    int c = threadIdx.x * 4;
    int beg = rowptr[node], end = rowptr[node + 1];
    ushort4 sv = *(const ushort4*)&hwS[(size_t)node * F + c];
    float a0 = b2f(sv.x), a1 = b2f(sv.y), a2 = b2f(sv.z), a3 = b2f(sv.w);
    for (int e = beg; e < end; ++e) {
        int s = csr_src[e];
        ushort4 v = *(const ushort4*)&hwS[(size_t)s * F + c];
        a0 += b2f(v.x); a1 += b2f(v.y); a2 += b2f(v.z); a3 += b2f(v.w);
    }
    float di = dinv[node];
    ushort4 rv = *(const ushort4*)&rres[(size_t)node * F + c];
    float4 vb = *(const float4*)&bc[c];
    float4 vbr = *(const float4*)&br[c];
    float o0 = fmaxf(fmaf(di, a0, vb.x), 0.f) + b2f(rv.x) + vbr.x;
    float o1 = fmaxf(fmaf(di, a1, vb.y), 0.f) + b2f(rv.y) + vbr.y;
    float o2 = fmaxf(fmaf(di, a2, vb.z), 0.f) + b2f(rv.z) + vbr.z;
    float o3 = fmaxf(fmaf(di, a3, vb.w), 0.f) + b2f(rv.w) + vbr.w;
    if (OUT_BF16) {
        unsigned short* op = (unsigned short*)out;
        ushort4 ov;
        ov.x = f2bf(o0); ov.y = f2bf(o1); ov.z = f2bf(o2); ov.w = f2bf(o3);
        *(ushort4*)&op[(size_t)node * F + c] = ov;
    } else {
        float* op = (float*)out;
        float4 ov = {o0, o1, o2, o3};
        *(float4*)&op[(size_t)node * F + c] = ov;
    }
}

// ---------------- final projection: out = [h2[:40000], istj] @ W_f + b_f ----------------
__global__ __launch_bounds__(256)
void k_final(const float* __restrict__ h2, const float* __restrict__ istj,
             const float* __restrict__ Wf, const float* __restrict__ bf,
             float* __restrict__ out) {
    __shared__ float w0[257], w1[257];
    int t = threadIdx.x;
    for (int i = t; i < 257; i += 256) {
        w0[i] = Wf[2 * i];
        w1[i] = Wf[2 * i + 1];
    }
    __syncthreads();
    int wave = t >> 6, lane = t & 63;
    int row = blockIdx.x * 4 + wave;
    if (row >= N_GENE) return;
    const float4 v = *(const float4*)&h2[(size_t)row * HID2 + lane * 4];
    int c = lane * 4;
    float s0 = v.x * w0[c] + v.y * w0[c + 1] + v.z * w0[c + 2] + v.w * w0[c + 3];
    float s1 = v.x * w1[c] + v.y * w1[c + 1] + v.z * w1[c + 2] + v.w * w1[c + 3];
    for (int off = 32; off > 0; off >>= 1) {
        s0 += __shfl_down(s0, off);
        s1 += __shfl_down(s1, off);
    }
    if (lane == 0) {
        float it = istj[row];
        out[(size_t)row * 2 + 0] = s0 + it * w0[256] + bf[0];
        out[(size_t)row * 2 + 1] = s1 + it * w1[256] + bf[1];
    }
}

extern "C" void kernel_launch(void* const* d_in, const int* in_sizes, int n_in,
                              void* d_out, int out_size, void* d_ws, size_t ws_size,
                              hipStream_t stream) {
    const float* x     = (const float*)d_in[0];
    const int*   ei    = (const int*)d_in[1];
    const float* istj  = (const float*)d_in[2];
    const float* W_go1 = (const float*)d_in[4];
    const float* b_go1 = (const float*)d_in[5];
    const float* W_go2 = (const float*)d_in[6];
    const float* b_go2 = (const float*)d_in[7];
    const float* W_c1  = (const float*)d_in[8];
    const float* b_c1  = (const float*)d_in[9];
    const float* W_c2  = (const float*)d_in[10];
    const float* b_c2  = (const float*)d_in[11];
    const float* W_r1  = (const float*)d_in[12];
    const float* b_r1  = (const float*)d_in[13];
    const float* W_r2  = (const float*)d_in[14];
    const float* b_r2  = (const float*)d_in[15];
    const float* W_f   = (const float*)d_in[16];
    const float* b_f   = (const float*)d_in[17];
    float* out = (float*)d_out;

    char* w = (char*)d_ws;
    size_t off = 0;
    auto alloc = [&](size_t bytes) -> void* {
        void* p = w + off;
        off += (bytes + 255) & ~(size_t)255;
        return p;
    };
    // region A: xt bf16 (later h1 bf16, in place)
    unsigned short* xt_bf = (unsigned short*)alloc((size_t)N_NODES * D_IN * 2);
    // region B: hwS bf16; early: g1 bf16 (10000*1024 <= 50000*512)
    unsigned short* bufB = (unsigned short*)alloc((size_t)N_NODES * D_IN * 2);
    unsigned short* g1_bf = bufB;
    // region C: r bf16; early: xg bf16 (10000*4096 > 50000*512 -> size for xg)
    unsigned short* bufC = (unsigned short*)alloc((size_t)N_GOID * GOID_DIM * 2);
    unsigned short* xg_bf = bufC;
    // region D: h2 fp32
    float* h2 = (float*)alloc((size_t)N_NODES * HID2 * 4);
    // weights bf16 transposed (NxK)
    unsigned short* Wgo1t = (unsigned short*)alloc((size_t)GO_HID * GOID_DIM * 2);
    unsigned short* Wgo2t = (unsigned short*)alloc((size_t)D_IN * GO_HID * 2);
    unsigned short* Wc1t  = (unsigned short*)alloc((size_t)HID1 * D_IN * 2);
    unsigned short* Wr1t  = (unsigned short*)alloc((size_t)HID1 * D_IN * 2);
    unsigned short* Wc2t  = (unsigned short*)alloc((size_t)HID2 * HID1 * 2);
    unsigned short* Wr2t  = (unsigned short*)alloc((size_t)HID2 * HID1 * 2);
    float* dinv = (float*)alloc((size_t)N_NODES * 4);
    int* counts = (int*)alloc((size_t)N_NODES * 4);
    int* rowptr = (int*)alloc((size_t)(N_NODES + 1) * 4);
    int* cursor = (int*)alloc((size_t)N_NODES * 4);
    int* csr    = (int*)alloc((size_t)N_EDGES * 4);

    const int* srcp = ei;
    const int* dstp = ei + N_EDGES;

    // CSR + degree norm
    k_zero<<<(N_NODES + 255) / 256, 256, 0, stream>>>(counts, N_NODES);
    k_count<<<(N_EDGES + 255) / 256, 256, 0, stream>>>(dstp, counts);
    k_scan<<<1, 1024, 0, stream>>>(counts, rowptr, cursor, dinv);
    k_fill<<<(N_EDGES + 255) / 256, 256, 0, stream>>>(srcp, dstp, cursor, csr);

    // conversions
    k_copy_gene_bf<<<(N_GENE * 64) / 256, 256, 0, stream>>>(x, xt_bf);
    k_f2bf8<<<(N_GOID * GOID_DIM / 8 + 255) / 256, 256, 0, stream>>>(
        x + (size_t)N_GENE * GOID_DIM, xg_bf, N_GOID * GOID_DIM / 8);
    k_wt<<<dim3(GO_HID / 32, GOID_DIM / 32), dim3(32, 8), 0, stream>>>(W_go1, Wgo1t, GOID_DIM, GO_HID);
    k_wt<<<dim3(D_IN / 32, GO_HID / 32), dim3(32, 8), 0, stream>>>(W_go2, Wgo2t, GO_HID, D_IN);
    k_wt<<<dim3(HID1 / 32, D_IN / 32), dim3(32, 8), 0, stream>>>(W_c1, Wc1t, D_IN, HID1);
    k_wt<<<dim3(HID1 / 32, D_IN / 32), dim3(32, 8), 0, stream>>>(W_r1, Wr1t, D_IN, HID1);
    k_wt<<<dim3(HID2 / 32, HID1 / 32), dim3(32, 8), 0, stream>>>(W_c2, Wc2t, HID1, HID2);
    k_wt<<<dim3(HID2 / 32, HID1 / 32), dim3(32, 8), 0, stream>>>(W_r2, Wr2t, HID1, HID2);

    // GOID MLP
    k_gemm_bf<EPI_BIAS_RELU><<<dim3(GO_HID / 128, (N_GOID + 127) / 128), 256, 0, stream>>>(
        xg_bf, Wgo1t, b_go1, nullptr, g1_bf, N_GOID, GO_HID, GOID_DIM);
    k_gemm_bf<EPI_BIAS_RELU><<<dim3(D_IN / 128, (N_GOID + 127) / 128), 256, 0, stream>>>(
        g1_bf, Wgo2t, b_go2, nullptr, xt_bf + (size_t)N_GENE * D_IN, N_GOID, D_IN, GO_HID);

    // conv1
    k_gemm_bf<EPI_SCALE><<<dim3(HID1 / 128, (N_NODES + 127) / 128), 256, 0, stream>>>(
        xt_bf, Wc1t, nullptr, dinv, bufB, N_NODES, HID1, D_IN);
    k_gemm_bf<EPI_PLAIN><<<dim3(HID1 / 128, (N_NODES + 127) / 128), 256, 0, stream>>>(
        xt_bf, Wr1t, nullptr, nullptr, bufC, N_NODES, HID1, D_IN);
    k_combine<HID1, true><<<N_NODES, HID1 / 4, 0, stream>>>(
        bufB, bufC, dinv, rowptr, csr, b_c1, b_r1, xt_bf);

    // conv2
    k_gemm_bf<EPI_SCALE><<<dim3(HID2 / 128, (N_NODES + 127) / 128), 256, 0, stream>>>(
        xt_bf, Wc2t, nullptr, dinv, bufB, N_NODES, HID2, HID1);
    k_gemm_bf<EPI_PLAIN><<<dim3(HID2 / 128, (N_NODES + 127) / 128), 256, 0, stream>>>(
        xt_bf, Wr2t, nullptr, nullptr, bufC, N_NODES, HID2, HID1);
    k_combine<HID2, false><<<N_NODES, HID2 / 4, 0, stream>>>(
        bufB, bufC, dinv, rowptr, csr, b_c2, b_r2, h2);

    // final projection
    k_final<<<(N_GENE + 3) / 4, 256, 0, stream>>>(h2, istj, W_f, b_f, out);
}